// Round 11
// baseline (722.090 us; speedup 1.0000x reference)
//
#include <hip/hip_runtime.h>
#include <math.h>

#define NNODES 100000
#define NEDGES 800000
#define NGRAPH 64
#define NHEAD  4
#define FINALD 512
#define HIDG   64
#define LATD   128
#define K1P    128  // layer-1 K padded (92 -> 128, BK=64 alignment)
#define NB_SCAN 98  // ceil(NNODES/1024)
#define PQ     16   // pool chunks per graph

typedef unsigned int uint;
typedef unsigned short ushort;
typedef __attribute__((ext_vector_type(8))) short bf16x8;
typedef __attribute__((ext_vector_type(4))) float f32x4;

// ---- bf16 helpers ----
__device__ __forceinline__ float bflo(uint u) { return __uint_as_float(u << 16); }
__device__ __forceinline__ float bfhi(uint u) { return __uint_as_float(u & 0xffff0000u); }
__device__ __forceinline__ ushort f2bf(float f) {
    uint u = __float_as_uint(f);
    return (ushort)((u + 0x7fffu + ((u >> 16) & 1u)) >> 16);
}
__device__ __forceinline__ uint pack2(float a, float b) {
    return (uint)f2bf(a) | ((uint)f2bf(b) << 16);
}
__device__ __forceinline__ void fmabf2(float w, uint v, float& a0, float& a1) {
    a0 = fmaf(w, bflo(v), a0);
    a1 = fmaf(w, bfhi(v), a1);
}

// ---- async global->LDS, 16B per lane, wave-uniform LDS base ----
__device__ __forceinline__ void async_copy16(const ushort* gsrc, ushort* lds_base) {
    __builtin_amdgcn_global_load_lds(
        (const __attribute__((address_space(1))) uint*)gsrc,
        (__attribute__((address_space(3))) uint*)lds_base,
        16, 0, 0);
}

// ======================== setup ========================
__global__ void count_kernel(const int* __restrict__ dst, int* __restrict__ deg) {
    int e = blockIdx.x * blockDim.x + threadIdx.x;
    if (e < NEDGES) atomicAdd(&deg[dst[e]], 1);
}
__global__ __launch_bounds__(1024) void scan_block_kernel(const int* __restrict__ deg,
                                                          int* __restrict__ off,
                                                          int* __restrict__ bsum) {
    __shared__ int buf[1024];
    int t = threadIdx.x;
    int i = blockIdx.x * 1024 + t;
    int x = (i < NNODES) ? deg[i] : 0;
    buf[t] = x;
    __syncthreads();
    for (int s = 1; s < 1024; s <<= 1) {
        int v = (t >= s) ? buf[t - s] : 0;
        __syncthreads();
        buf[t] += v;
        __syncthreads();
    }
    if (i < NNODES) off[i] = buf[t] - x;
    if (t == 1023) bsum[blockIdx.x] = buf[1023];
}
__global__ __launch_bounds__(128) void scan_bsum_kernel(int* __restrict__ bsum) {
    __shared__ int buf[128];
    int t = threadIdx.x;
    int x = (t < NB_SCAN) ? bsum[t] : 0;
    buf[t] = x;
    __syncthreads();
    for (int s = 1; s < 128; s <<= 1) {
        int v = (t >= s) ? buf[t - s] : 0;
        __syncthreads();
        buf[t] += v;
        __syncthreads();
    }
    if (t < NB_SCAN) bsum[t] = buf[t] - x;
    if (t == 0) bsum[NB_SCAN] = buf[NB_SCAN - 1];
}
__global__ __launch_bounds__(1024) void scan_add_kernel(int* __restrict__ off,
                                                        const int* __restrict__ bsum,
                                                        int* __restrict__ cursor) {
    int i = blockIdx.x * 1024 + threadIdx.x;
    if (i < NNODES) {
        int v = off[i] + bsum[blockIdx.x];
        off[i] = v;
        cursor[i] = v;
    }
    if (i == 0) off[NNODES] = bsum[NB_SCAN];
}
// also emits dst per CSR slot (needed by edge-parallel attn)
__global__ void scatter_kernel(const int* __restrict__ src, const int* __restrict__ dst,
                               int* __restrict__ cursor, int* __restrict__ src_csr,
                               int* __restrict__ dst_csr) {
    int e = blockIdx.x * blockDim.x + threadIdx.x;
    if (e >= NEDGES) return;
    int d = dst[e];
    int p = atomicAdd(&cursor[d], 1);
    src_csr[p] = src[e];
    dst_csr[p] = d;
}

// ======================== combined conversions + gate/deg zero + gstart ========================
#define C1 (128 * K1P)
#define C2 (256 * 128)
#define C3 (512 * 256)
#define CG (64 * 512)
#define CX (NNODES * K1P)
#define CTOT (C1 + C2 + C3 + CG + CX + NNODES + NNODES + NGRAPH + 1)
__global__ void conv_all_kernel(const float* __restrict__ W1, const float* __restrict__ W2,
                                const float* __restrict__ W3, const float* __restrict__ Wg1,
                                const float* __restrict__ nf,
                                ushort* __restrict__ Bt1, ushort* __restrict__ Bt2,
                                ushort* __restrict__ Bt3, ushort* __restrict__ Btg,
                                ushort* __restrict__ x0, float* __restrict__ gate,
                                int* __restrict__ deg, const int* __restrict__ gid,
                                int* __restrict__ gstart) {
    int i = blockIdx.x * blockDim.x + threadIdx.x;
    if (i < C1) {
        int n = i >> 7, k = i & 127;
        Bt1[i] = (k < 92) ? f2bf(W1[(size_t)k * 128 + n]) : (ushort)0;
        return;
    }
    i -= C1;
    if (i < C2) {
        int n = i >> 7, k = i & 127;
        Bt2[i] = f2bf(W2[(size_t)k * 256 + n]);
        return;
    }
    i -= C2;
    if (i < C3) {
        int n = i >> 8, k = i & 255;
        Bt3[i] = f2bf(W3[(size_t)k * 512 + n]);
        return;
    }
    i -= C3;
    if (i < CG) {
        int n = i >> 9, k = i & 511;
        Btg[i] = f2bf(Wg1[(size_t)k * 64 + n]);
        return;
    }
    i -= CG;
    if (i < CX) {
        int n = i >> 7, k = i & 127;
        x0[i] = (k < 92) ? f2bf(nf[(size_t)n * 92 + k]) : (ushort)0;
        return;
    }
    i -= CX;
    if (i < NNODES) { gate[i] = 0.f; return; }
    i -= NNODES;
    if (i < NNODES) { deg[i] = 0; return; }
    i -= NNODES;
    if (i <= NGRAPH) {
        int lo = 0, hi = NNODES;
        while (lo < hi) {
            int mid = (lo + hi) >> 1;
            if (gid[mid] < i) lo = mid + 1; else hi = mid;
        }
        gstart[i] = lo;
    }
}

// ======================== MFMA bf16 GEMM (BK=64, async global_load_lds staging) ============
// grid = (colBlocks, rowBlocks). MODE 0: direct bf16 C store. MODE 1: fused gate epilogue.
// K-step = 64 (halves barrier/vmcnt-drain count vs BK=32). LDS tiles [rows][64] ushort
// (128B rows), dest linear; XOR piece-swizzle (3-bit involution, keyed by row&7):
//   stored piece = (l&7) ^ (l>>3);  read piece = (ks*4+quad) ^ (l16&7)
// -> per-16-lane group: 8 slots x 2 lanes = minimum aliasing (free per m136).
// OOB A rows (row >= M) read garbage from adjacent ws buffers; outputs masked.
template <int BN, int MODE>
__global__ __launch_bounds__(256) void mfma_gemm(const ushort* __restrict__ A,
                                                 const ushort* __restrict__ Bt,
                                                 const float* __restrict__ bias,
                                                 ushort* __restrict__ C,
                                                 const float* __restrict__ Wg2,
                                                 float* __restrict__ gate,
                                                 int M, int K, int N) {
    constexpr int WNS = BN / 2;
    constexpr int NT = WNS / 16;
    __shared__ ushort Alds[128][64];
    __shared__ ushort Blds[BN][64];
    int tid = threadIdx.x;
    int wave = tid >> 6, lane = tid & 63;
    int wm = wave & 1, wn = wave >> 1;
    int quad = lane >> 4, l16 = lane & 15;
    int rowBase = blockIdx.y * 128;
    int colBase = blockIdx.x * BN;

    // staging geometry: chunk = 8 rows x 128B; lane -> (row l>>3, swizzled 16B piece)
    int srow8 = lane >> 3;
    int scol = ((lane & 7) ^ srow8) * 8;  // ushort offset of the 16B piece
    // fragment-read piece offsets for the two K-sub-steps (same involution, key = l16&7)
    int rp0 = ((quad) ^ (l16 & 7)) * 8;
    int rp1 = ((4 + quad) ^ (l16 & 7)) * 8;

    f32x4 acc[4][NT];
#pragma unroll
    for (int i = 0; i < 4; i++)
#pragma unroll
        for (int j = 0; j < NT; j++) acc[i][j] = (f32x4){0.f, 0.f, 0.f, 0.f};

    for (int k0 = 0; k0 < K; k0 += 64) {
        // stage A: 128 rows = 16 chunks of 8 rows; wave w handles chunks 4w..4w+3
#pragma unroll
        for (int c = 0; c < 4; c++) {
            int chunk = wave * 4 + c;
            int row = rowBase + chunk * 8 + srow8;
            async_copy16(&A[(size_t)row * K + k0 + scol], &Alds[chunk * 8][0]);
        }
        // stage B
        if constexpr (BN == 128) {
#pragma unroll
            for (int c = 0; c < 4; c++) {
                int chunk = wave * 4 + c;
                int row = colBase + chunk * 8 + srow8;
                async_copy16(&Bt[(size_t)row * K + k0 + scol], &Blds[chunk * 8][0]);
            }
        } else {  // BN == 64: 8 chunks, two per wave
#pragma unroll
            for (int c = 0; c < 2; c++) {
                int chunk = wave * 2 + c;
                int row = colBase + chunk * 8 + srow8;
                async_copy16(&Bt[(size_t)row * K + k0 + scol], &Blds[chunk * 8][0]);
            }
        }
        __syncthreads();
        // two MFMA sub-steps from one staged tile
        {
            bf16x8 af[4], bf[NT];
#pragma unroll
            for (int i = 0; i < 4; i++)
                af[i] = *(const bf16x8*)&Alds[wm * 64 + i * 16 + l16][rp0];
#pragma unroll
            for (int j = 0; j < NT; j++)
                bf[j] = *(const bf16x8*)&Blds[wn * WNS + j * 16 + l16][rp0];
#pragma unroll
            for (int i = 0; i < 4; i++)
#pragma unroll
                for (int j = 0; j < NT; j++)
                    acc[i][j] = __builtin_amdgcn_mfma_f32_16x16x32_bf16(af[i], bf[j], acc[i][j], 0, 0, 0);
        }
        {
            bf16x8 af[4], bf[NT];
#pragma unroll
            for (int i = 0; i < 4; i++)
                af[i] = *(const bf16x8*)&Alds[wm * 64 + i * 16 + l16][rp1];
#pragma unroll
            for (int j = 0; j < NT; j++)
                bf[j] = *(const bf16x8*)&Blds[wn * WNS + j * 16 + l16][rp1];
#pragma unroll
            for (int i = 0; i < 4; i++)
#pragma unroll
                for (int j = 0; j < NT; j++)
                    acc[i][j] = __builtin_amdgcn_mfma_f32_16x16x32_bf16(af[i], bf[j], acc[i][j], 0, 0, 0);
        }
        __syncthreads();
    }

    if constexpr (MODE == 0) {
#pragma unroll
        for (int i = 0; i < 4; i++) {
#pragma unroll
            for (int j = 0; j < NT; j++) {
                int col = colBase + wn * WNS + j * 16 + l16;
#pragma unroll
                for (int r = 0; r < 4; r++) {
                    int row = rowBase + wm * 64 + i * 16 + quad * 4 + r;
                    if (row < M) C[(size_t)row * N + col] = f2bf(acc[i][j][r]);
                }
            }
        }
    } else {
        float bb[NT], wg[NT];
#pragma unroll
        for (int j = 0; j < NT; j++) {
            int col = colBase + wn * WNS + j * 16 + l16;
            bb[j] = bias[col];
            wg[j] = Wg2[col];
        }
#pragma unroll
        for (int i = 0; i < 4; i++) {
            float pd[4] = {0.f, 0.f, 0.f, 0.f};
#pragma unroll
            for (int j = 0; j < NT; j++) {
#pragma unroll
                for (int r = 0; r < 4; r++) {
                    float x = fmaxf(acc[i][j][r] + bb[j], 0.f);
                    pd[r] = fmaf(x, wg[j], pd[r]);
                }
            }
#pragma unroll
            for (int m = 1; m < 16; m <<= 1)
#pragma unroll
                for (int r = 0; r < 4; r++)
                    pd[r] += __shfl_xor(pd[r], m, 64);
            if (l16 == 0) {
#pragma unroll
                for (int r = 0; r < 4; r++) {
                    int row = rowBase + wm * 64 + i * 16 + quad * 4 + r;
                    if (row < M) atomicAdd(&gate[row], pd[r]);
                }
            }
        }
    }
}

// ======================== el/er: multi-node-per-wave, vectorized ========================
template <int HD>
__global__ __launch_bounds__(256) void eler_node(const ushort* __restrict__ Wh,
                                                 const float* __restrict__ al,
                                                 const float* __restrict__ ar,
                                                 float* __restrict__ el,
                                                 float* __restrict__ er) {
    constexpr int LPN = HD / 8;
    constexpr int NPW = 64 / LPN;
    constexpr int S = (HD / NHEAD) / 8;
    int wave = threadIdx.x >> 6;
    int lane = threadIdx.x & 63;
    int sub = lane & (LPN - 1);
    int n = blockIdx.x * (4 * NPW) + wave * NPW + lane / LPN;
    int d0 = sub * 8;
    uint4 v = *(const uint4*)&Wh[(size_t)n * HD + d0];
    float w0 = bflo(v.x), w1 = bfhi(v.x), w2 = bflo(v.y), w3 = bfhi(v.y);
    float w4 = bflo(v.z), w5 = bfhi(v.z), w6 = bflo(v.w), w7 = bfhi(v.w);
    float4 a0 = *(const float4*)&al[d0];
    float4 a1 = *(const float4*)&al[d0 + 4];
    float4 b0 = *(const float4*)&ar[d0];
    float4 b1 = *(const float4*)&ar[d0 + 4];
    float sl, sr;
    sl = w0 * a0.x; sl = fmaf(w1, a0.y, sl); sl = fmaf(w2, a0.z, sl); sl = fmaf(w3, a0.w, sl);
    sl = fmaf(w4, a1.x, sl); sl = fmaf(w5, a1.y, sl); sl = fmaf(w6, a1.z, sl); sl = fmaf(w7, a1.w, sl);
    sr = w0 * b0.x; sr = fmaf(w1, b0.y, sr); sr = fmaf(w2, b0.z, sr); sr = fmaf(w3, b0.w, sr);
    sr = fmaf(w4, b1.x, sr); sr = fmaf(w5, b1.y, sr); sr = fmaf(w6, b1.z, sr); sr = fmaf(w7, b1.w, sr);
#pragma unroll
    for (int o = S / 2; o > 0; o >>= 1) {
        sl += __shfl_down(sl, o, 64);
        sr += __shfl_down(sr, o, 64);
    }
    if ((sub & (S - 1)) == 0) {
        int h = sub / S;
        el[n * 4 + h] = sl;
        er[n * 4 + h] = sr;
    }
}

// ======================== edge-parallel attn: one thread per CSR slot ========================
// w = exp(leaky(el[src]+er[dst]) - 8): fixed shift replaces per-node max (softmax
// shift-invariance; scores O(1), overflow needs >96, denominator underflow needs all
// < -12 — impossible here). Fully parallel: 800k threads, no per-node serial loop.
// Denominator is accumulated inside the aggregate (1 VALU add per edge per lane).
__global__ void attn_edge(const int* __restrict__ src_csr, const int* __restrict__ dst_csr,
                          const float4* __restrict__ el4, const float4* __restrict__ er4,
                          float4* __restrict__ aw4) {
    int i = blockIdx.x * blockDim.x + threadIdx.x;
    if (i >= NEDGES) return;
    int s = src_csr[i];
    int d = dst_csr[i];
    float4 a = el4[s];
    float4 b = er4[d];
    float x0 = a.x + b.x, x1 = a.y + b.y, x2 = a.z + b.z, x3 = a.w + b.w;
    x0 = (x0 >= 0.f) ? x0 : 0.2f * x0;
    x1 = (x1 >= 0.f) ? x1 : 0.2f * x1;
    x2 = (x2 >= 0.f) ? x2 : 0.2f * x2;
    x3 = (x3 >= 0.f) ? x3 : 0.2f * x3;
    float4 w;
    w.x = expf(x0 - 8.f); w.y = expf(x1 - 8.f);
    w.z = expf(x2 - 8.f); w.w = expf(x3 - 8.f);
    aw4[i] = w;
}

// ======================== aggregate v2b: wave/node, SGPR gather, local denominator ========
// Wave w of block b owns node n = b*4 + w. Lane covers DPL dims starting at
// pass*64*DPL + lane*DPL. Src indices / offsets forced to SGPRs via readfirstlane ->
// SALU addressing, saddr-form gathers. Softmax denominator accumulated from the
// weights each lane loads anyway (1 add/edge; lanes sharing a head duplicate it).
template <int HD, int DPL>
__global__ __launch_bounds__(256) void gat_aggregate2(const int* __restrict__ src_csr,
                                                      const int* __restrict__ off,
                                                      const ushort* __restrict__ Wh,
                                                      const float* __restrict__ aw,
                                                      const float* __restrict__ bias,
                                                      ushort* __restrict__ out,
                                                      int pass) {
    constexpr int LOGD = (HD == 128) ? 5 : (HD == 256) ? 6 : 7;
    const int lane = threadIdx.x & 63;
    const int wv = __builtin_amdgcn_readfirstlane((int)(threadIdx.x >> 6));
    const int n = blockIdx.x * 4 + wv;
    const int d = pass * (64 * DPL) + lane * DPL;
    const int h = d >> LOGD;
    const int i0 = __builtin_amdgcn_readfirstlane(off[n]);
    const int i1 = __builtin_amdgcn_readfirstlane(off[n + 1]);

    float a0 = 0.f, a1 = 0.f, a2 = 0.f, a3 = 0.f;
    float ssum = 0.f;
    const ushort* __restrict__ col = Wh + d;  // per-lane column base; row offset is SGPR

    int i = i0;
    for (; i + 4 <= i1; i += 4) {
        const int s0 = __builtin_amdgcn_readfirstlane(src_csr[i + 0]);
        const int s1 = __builtin_amdgcn_readfirstlane(src_csr[i + 1]);
        const int s2 = __builtin_amdgcn_readfirstlane(src_csr[i + 2]);
        const int s3 = __builtin_amdgcn_readfirstlane(src_csr[i + 3]);
        const float w0 = aw[(i + 0) * 4 + h];
        const float w1 = aw[(i + 1) * 4 + h];
        const float w2 = aw[(i + 2) * 4 + h];
        const float w3 = aw[(i + 3) * 4 + h];
        ssum += w0; ssum += w1; ssum += w2; ssum += w3;
        if constexpr (DPL == 4) {
            uint2 v0 = *(const uint2*)&col[(size_t)s0 * HD];
            uint2 v1 = *(const uint2*)&col[(size_t)s1 * HD];
            uint2 v2 = *(const uint2*)&col[(size_t)s2 * HD];
            uint2 v3 = *(const uint2*)&col[(size_t)s3 * HD];
            fmabf2(w0, v0.x, a0, a1); fmabf2(w0, v0.y, a2, a3);
            fmabf2(w1, v1.x, a0, a1); fmabf2(w1, v1.y, a2, a3);
            fmabf2(w2, v2.x, a0, a1); fmabf2(w2, v2.y, a2, a3);
            fmabf2(w3, v3.x, a0, a1); fmabf2(w3, v3.y, a2, a3);
        } else {
            uint v0 = *(const uint*)&col[(size_t)s0 * HD];
            uint v1 = *(const uint*)&col[(size_t)s1 * HD];
            uint v2 = *(const uint*)&col[(size_t)s2 * HD];
            uint v3 = *(const uint*)&col[(size_t)s3 * HD];
            fmabf2(w0, v0, a0, a1);
            fmabf2(w1, v1, a0, a1);
            fmabf2(w2, v2, a0, a1);
            fmabf2(w3, v3, a0, a1);
        }
    }
    for (; i < i1; ++i) {
        const int s0 = __builtin_amdgcn_readfirstlane(src_csr[i]);
        const float w0 = aw[i * 4 + h];
        ssum += w0;
        if constexpr (DPL == 4) {
            uint2 v0 = *(const uint2*)&col[(size_t)s0 * HD];
            fmabf2(w0, v0.x, a0, a1); fmabf2(w0, v0.y, a2, a3);
        } else {
            uint v0 = *(const uint*)&col[(size_t)s0 * HD];
            fmabf2(w0, v0, a0, a1);
        }
    }

    const float inv = 1.f / fmaxf(ssum, 1e-9f);
    float x0 = a0 * inv + bias[d + 0];
    float x1 = a1 * inv + bias[d + 1];
    x0 = (x0 > 0.f) ? x0 : (expf(x0) - 1.f);
    x1 = (x1 > 0.f) ? x1 : (expf(x1) - 1.f);
    if constexpr (DPL == 4) {
        float x2 = a2 * inv + bias[d + 2];
        float x3 = a3 * inv + bias[d + 3];
        x2 = (x2 > 0.f) ? x2 : (expf(x2) - 1.f);
        x3 = (x3 > 0.f) ? x3 : (expf(x3) - 1.f);
        uint2 o;
        o.x = pack2(x0, x1);
        o.y = pack2(x2, x3);
        *(uint2*)&out[(size_t)n * HD + d] = o;
    } else {
        *(uint*)&out[(size_t)n * HD + d] = pack2(x0, x1);
    }
}

// ======================== pooled partial sums + fused per-graph softmax ========================
// Each block (g,q) recomputes its graph's gate max m (deterministic: identical
// strided partition + LDS tree in every block of graph g), then pools its node
// chunk with w = exp(gate-m). Denominator is applied in final_kernel.
__global__ __launch_bounds__(128) void pool_partial(const ushort* __restrict__ h,
                                                    const float* __restrict__ gate,
                                                    const int* __restrict__ gstart,
                                                    float* __restrict__ partial) {
    int g = blockIdx.x, q = blockIdx.y;
    int n0 = gstart[g], n1 = gstart[g + 1];
    __shared__ float red[128];
    int t = threadIdx.x;
    float m = -1e30f;
    for (int n = n0 + t; n < n1; n += 128) m = fmaxf(m, gate[n]);
    red[t] = m; __syncthreads();
    for (int s = 64; s > 0; s >>= 1) {
        if (t < s) red[t] = fmaxf(red[t], red[t + s]);
        __syncthreads();
    }
    m = red[0];

    int len = n1 - n0;
    int chunk = (len + PQ - 1) / PQ;
    int s = n0 + q * chunk;
    int e = s + chunk; if (e > n1) e = n1;
    int d4 = t;
    const uint2* h2 = (const uint2*)h;
    float a0 = 0.f, a1 = 0.f, a2 = 0.f, a3 = 0.f;
    for (int n = s; n < e; n++) {
        float w = expf(gate[n] - m);
        uint2 v = h2[(size_t)n * 128 + d4];
        a0 = fmaf(w, bflo(v.x), a0);
        a1 = fmaf(w, bfhi(v.x), a1);
        a2 = fmaf(w, bflo(v.y), a2);
        a3 = fmaf(w, bfhi(v.y), a3);
    }
    *(float4*)&partial[((size_t)(g * PQ + q)) * FINALD + d4 * 4] = make_float4(a0, a1, a2, a3);
}

// ======================== final heads (computes graph softmax denominator) ========================
__global__ __launch_bounds__(128) void final_kernel(const float* __restrict__ partial,
                                                    const float* __restrict__ gate,
                                                    const int* __restrict__ gstart,
                                                    const float* __restrict__ Wmu,
                                                    const float* __restrict__ bmu,
                                                    const float* __restrict__ Wlv,
                                                    const float* __restrict__ blv,
                                                    float* __restrict__ out) {
    int g = blockIdx.x, j = threadIdx.x;
    int n0 = gstart[g], n1 = gstart[g + 1];
    __shared__ float red[128];
    __shared__ float pooled[FINALD];
    // gsum = sum exp(gate - m), same deterministic m as pool_partial
    float m = -1e30f;
    for (int n = n0 + j; n < n1; n += 128) m = fmaxf(m, gate[n]);
    red[j] = m; __syncthreads();
    for (int s = 64; s > 0; s >>= 1) {
        if (j < s) red[j] = fmaxf(red[j], red[j + s]);
        __syncthreads();
    }
    m = red[0]; __syncthreads();
    float sum = 0.f;
    for (int n = n0 + j; n < n1; n += 128) sum += expf(gate[n] - m);
    red[j] = sum; __syncthreads();
    for (int s = 64; s > 0; s >>= 1) {
        if (j < s) red[j] += red[j + s];
        __syncthreads();
    }
    float gsum = red[0];

    const float* p = partial + (size_t)g * PQ * FINALD;
    for (int k = j; k < FINALD; k += 128) {
        float v = 0.f;
#pragma unroll
        for (int q = 0; q < PQ; q++) v += p[q * FINALD + k];
        pooled[k] = v;
    }
    __syncthreads();
    float am = 0.f, av = 0.f;
    for (int k = 0; k < FINALD; k++) {
        float pv = pooled[k];
        am = fmaf(pv, Wmu[k * LATD + j], am);
        av = fmaf(pv, Wlv[k * LATD + j], av);
    }
    float inv = 1.f / fmaxf(gsum, 1e-9f);
    out[g * LATD + j] = am * inv + bmu[j];
    out[NGRAPH * LATD + g * LATD + j] = av * inv + blv[j];
}

// ======================== driver ========================
extern "C" void kernel_launch(void* const* d_in, const int* in_sizes, int n_in,
                              void* d_out, int out_size, void* d_ws, size_t ws_size,
                              hipStream_t stream) {
    (void)in_sizes; (void)n_in; (void)out_size; (void)ws_size;
    const float* node_feat = (const float*)d_in[0];
    const int* src = (const int*)d_in[1];
    const int* dst = (const int*)d_in[2];
    const int* gid = (const int*)d_in[3];
    const float* W[3]    = {(const float*)d_in[4],  (const float*)d_in[8],  (const float*)d_in[12]};
    const float* al[3]   = {(const float*)d_in[5],  (const float*)d_in[9],  (const float*)d_in[13]};
    const float* ar[3]   = {(const float*)d_in[6],  (const float*)d_in[10], (const float*)d_in[14]};
    const float* bias[3] = {(const float*)d_in[7],  (const float*)d_in[11], (const float*)d_in[15]};
    const float* Wg1 = (const float*)d_in[16];
    const float* bg1 = (const float*)d_in[17];
    const float* Wg2 = (const float*)d_in[18];
    // bg2 cancels in the node softmax — unused.
    const float* Wmu = (const float*)d_in[20];
    const float* bmu = (const float*)d_in[21];
    const float* Wlv = (const float*)d_in[22];
    const float* blv = (const float*)d_in[23];

    char* ws = (char*)d_ws;
    size_t woff = 0;
    auto carve = [&](size_t bytes) {
        void* p = ws + woff;
        woff = (woff + bytes + 255) & ~(size_t)255;
        return p;
    };
    ushort* hA      = (ushort*)carve((size_t)NNODES * 512 * 2);
    ushort* hB      = (ushort*)carve((size_t)NNODES * 512 * 2);
    float*  el      = (float*) carve((size_t)NNODES * 4 * 4);
    float*  er      = (float*) carve((size_t)NNODES * 4 * 4);
    float*  aw      = (float*) carve((size_t)NEDGES * 4 * 4);
    int*    deg     = (int*)   carve((size_t)NNODES * 4);
    int*    off     = (int*)   carve((size_t)(NNODES + 1) * 4);
    int*    cursor  = (int*)   carve((size_t)NNODES * 4);
    int*    src_csr = (int*)   carve((size_t)NEDGES * 4);
    int*    dst_csr = (int*)   carve((size_t)NEDGES * 4);
    int*    bsum    = (int*)   carve((size_t)(NB_SCAN + 1) * 4);
    float*  gate    = (float*) carve((size_t)NNODES * 4);
    int*    gstart  = (int*)   carve((size_t)(NGRAPH + 1) * 4);
    float*  partial = (float*) carve((size_t)NGRAPH * PQ * FINALD * 4);
    ushort* Bt1     = (ushort*)carve((size_t)128 * K1P * 2);
    ushort* Bt2     = (ushort*)carve((size_t)256 * 128 * 2);
    ushort* Bt3     = (ushort*)carve((size_t)512 * 256 * 2);
    ushort* Btg     = (ushort*)carve((size_t)64 * 512 * 2 + 4096);  // +4KB guard for async OOB reads
    ushort* x0      = hA;  // alias: x0 dead before hA first written (L1 aggregate)

    // ---- setup (6 launches; conv_all also zeros deg/gate + computes gstart) ----
    conv_all_kernel<<<(CTOT + 255) / 256, 256, 0, stream>>>(
        W[0], W[1], W[2], Wg1, node_feat, Bt1, Bt2, Bt3, Btg, x0, gate, deg, gid, gstart);
    count_kernel<<<(NEDGES + 255) / 256, 256, 0, stream>>>(dst, deg);
    scan_block_kernel<<<NB_SCAN, 1024, 0, stream>>>(deg, off, bsum);
    scan_bsum_kernel<<<1, 128, 0, stream>>>(bsum);
    scan_add_kernel<<<NB_SCAN, 1024, 0, stream>>>(off, bsum, cursor);
    scatter_kernel<<<(NEDGES + 255) / 256, 256, 0, stream>>>(src, dst, cursor, src_csr, dst_csr);

    const int MB = (NNODES + 127) / 128;  // 782
    const int AGB = NNODES / 4;           // 25000 blocks, 4 waves (nodes) each
    const int EB = (NEDGES + 255) / 256;  // 3125 edge blocks

    // ---- layer 1 (K padded to 128) ----
    mfma_gemm<128, 0><<<dim3(1, MB), 256, 0, stream>>>(
        x0, Bt1, nullptr, hB, nullptr, nullptr, NNODES, K1P, 128);
    eler_node<128><<<NNODES / 16, 256, 0, stream>>>(hB, al[0], ar[0], el, er);
    attn_edge<<<EB, 256, 0, stream>>>(
        src_csr, dst_csr, (const float4*)el, (const float4*)er, (float4*)aw);
    gat_aggregate2<128, 2><<<AGB, 256, 0, stream>>>(
        src_csr, off, hB, aw, bias[0], hA, 0);

    // ---- layer 2 ----
    mfma_gemm<128, 0><<<dim3(2, MB), 256, 0, stream>>>(
        hA, Bt2, nullptr, hB, nullptr, nullptr, NNODES, 128, 256);
    eler_node<256><<<NNODES / 8, 256, 0, stream>>>(hB, al[1], ar[1], el, er);
    attn_edge<<<EB, 256, 0, stream>>>(
        src_csr, dst_csr, (const float4*)el, (const float4*)er, (float4*)aw);
    gat_aggregate2<256, 4><<<AGB, 256, 0, stream>>>(
        src_csr, off, hB, aw, bias[1], hA, 0);

    // ---- layer 3 (two dim-passes: measured champion config) ----
    mfma_gemm<128, 0><<<dim3(4, MB), 256, 0, stream>>>(
        hA, Bt3, nullptr, hB, nullptr, nullptr, NNODES, 256, 512);
    eler_node<512><<<NNODES / 4, 256, 0, stream>>>(hB, al[2], ar[2], el, er);
    attn_edge<<<EB, 256, 0, stream>>>(
        src_csr, dst_csr, (const float4*)el, (const float4*)er, (float4*)aw);
    gat_aggregate2<512, 4><<<AGB, 256, 0, stream>>>(
        src_csr, off, hB, aw, bias[2], hA, 0);
    gat_aggregate2<512, 4><<<AGB, 256, 0, stream>>>(
        src_csr, off, hB, aw, bias[2], hA, 1);

    // ---- attention pooling + heads (3 launches; softmax fused into pool/final) ----
    mfma_gemm<64, 1><<<dim3(1, MB), 256, 0, stream>>>(
        hA, Btg, bg1, nullptr, Wg2, gate, NNODES, FINALD, HIDG);
    pool_partial<<<dim3(NGRAPH, PQ), 128, 0, stream>>>(hA, gate, gstart, partial);
    final_kernel<<<NGRAPH, 128, 0, stream>>>(partial, gate, gstart, Wmu, bmu, Wlv, blv, (float*)d_out);
}

// Round 12
// 715.697 us; speedup vs baseline: 1.0089x; 1.0089x over previous
//
#include <hip/hip_runtime.h>
#include <math.h>

#define NNODES 100000
#define NEDGES 800000
#define NGRAPH 64
#define NHEAD  4
#define FINALD 512
#define HIDG   64
#define LATD   128
#define K1P    96   // layer-1 K padded (92 -> 96, BK=32 path)
#define NB_SCAN 98  // ceil(NNODES/1024)
#define PQ     16   // pool chunks per graph

typedef unsigned int uint;
typedef unsigned short ushort;
typedef __attribute__((ext_vector_type(8))) short bf16x8;
typedef __attribute__((ext_vector_type(4))) float f32x4;

// ---- bf16 helpers ----
__device__ __forceinline__ float bflo(uint u) { return __uint_as_float(u << 16); }
__device__ __forceinline__ float bfhi(uint u) { return __uint_as_float(u & 0xffff0000u); }
__device__ __forceinline__ ushort f2bf(float f) {
    uint u = __float_as_uint(f);
    return (ushort)((u + 0x7fffu + ((u >> 16) & 1u)) >> 16);
}
__device__ __forceinline__ uint pack2(float a, float b) {
    return (uint)f2bf(a) | ((uint)f2bf(b) << 16);
}
__device__ __forceinline__ void fmabf2(float w, uint v, float& a0, float& a1) {
    a0 = fmaf(w, bflo(v), a0);
    a1 = fmaf(w, bfhi(v), a1);
}

// ---- async global->LDS, 16B per lane, wave-uniform LDS base ----
__device__ __forceinline__ void async_copy16(const ushort* gsrc, ushort* lds_base) {
    __builtin_amdgcn_global_load_lds(
        (const __attribute__((address_space(1))) uint*)gsrc,
        (__attribute__((address_space(3))) uint*)lds_base,
        16, 0, 0);
}

// ======================== setup ========================
__global__ void count_kernel(const int* __restrict__ dst, int* __restrict__ deg) {
    int e = blockIdx.x * blockDim.x + threadIdx.x;
    if (e < NEDGES) atomicAdd(&deg[dst[e]], 1);
}
__global__ __launch_bounds__(1024) void scan_block_kernel(const int* __restrict__ deg,
                                                          int* __restrict__ off,
                                                          int* __restrict__ bsum) {
    __shared__ int buf[1024];
    int t = threadIdx.x;
    int i = blockIdx.x * 1024 + t;
    int x = (i < NNODES) ? deg[i] : 0;
    buf[t] = x;
    __syncthreads();
    for (int s = 1; s < 1024; s <<= 1) {
        int v = (t >= s) ? buf[t - s] : 0;
        __syncthreads();
        buf[t] += v;
        __syncthreads();
    }
    if (i < NNODES) off[i] = buf[t] - x;
    if (t == 1023) bsum[blockIdx.x] = buf[1023];
}
__global__ __launch_bounds__(128) void scan_bsum_kernel(int* __restrict__ bsum) {
    __shared__ int buf[128];
    int t = threadIdx.x;
    int x = (t < NB_SCAN) ? bsum[t] : 0;
    buf[t] = x;
    __syncthreads();
    for (int s = 1; s < 128; s <<= 1) {
        int v = (t >= s) ? buf[t - s] : 0;
        __syncthreads();
        buf[t] += v;
        __syncthreads();
    }
    if (t < NB_SCAN) bsum[t] = buf[t] - x;
    if (t == 0) bsum[NB_SCAN] = buf[NB_SCAN - 1];
}
__global__ __launch_bounds__(1024) void scan_add_kernel(int* __restrict__ off,
                                                        const int* __restrict__ bsum,
                                                        int* __restrict__ cursor) {
    int i = blockIdx.x * 1024 + threadIdx.x;
    if (i < NNODES) {
        int v = off[i] + bsum[blockIdx.x];
        off[i] = v;
        cursor[i] = v;
    }
    if (i == 0) off[NNODES] = bsum[NB_SCAN];
}
// also emits dst per CSR slot (needed by edge-parallel attn)
__global__ void scatter_kernel(const int* __restrict__ src, const int* __restrict__ dst,
                               int* __restrict__ cursor, int* __restrict__ src_csr,
                               int* __restrict__ dst_csr) {
    int e = blockIdx.x * blockDim.x + threadIdx.x;
    if (e >= NEDGES) return;
    int d = dst[e];
    int p = atomicAdd(&cursor[d], 1);
    src_csr[p] = src[e];
    dst_csr[p] = d;
}

// ======================== combined conversions + gate/deg zero + gstart ========================
#define C1 (128 * K1P)
#define C2 (256 * 128)
#define C3 (512 * 256)
#define CG (64 * 512)
#define CX (NNODES * K1P)
#define CTOT (C1 + C2 + C3 + CG + CX + NNODES + NNODES + NGRAPH + 1)
__global__ void conv_all_kernel(const float* __restrict__ W1, const float* __restrict__ W2,
                                const float* __restrict__ W3, const float* __restrict__ Wg1,
                                const float* __restrict__ nf,
                                ushort* __restrict__ Bt1, ushort* __restrict__ Bt2,
                                ushort* __restrict__ Bt3, ushort* __restrict__ Btg,
                                ushort* __restrict__ x0, float* __restrict__ gate,
                                int* __restrict__ deg, const int* __restrict__ gid,
                                int* __restrict__ gstart) {
    int i = blockIdx.x * blockDim.x + threadIdx.x;
    if (i < C1) {
        int n = i / K1P, k = i - n * K1P;
        Bt1[i] = (k < 92) ? f2bf(W1[(size_t)k * 128 + n]) : (ushort)0;
        return;
    }
    i -= C1;
    if (i < C2) {
        int n = i >> 7, k = i & 127;
        Bt2[i] = f2bf(W2[(size_t)k * 256 + n]);
        return;
    }
    i -= C2;
    if (i < C3) {
        int n = i >> 8, k = i & 255;
        Bt3[i] = f2bf(W3[(size_t)k * 512 + n]);
        return;
    }
    i -= C3;
    if (i < CG) {
        int n = i >> 9, k = i & 511;
        Btg[i] = f2bf(Wg1[(size_t)k * 64 + n]);
        return;
    }
    i -= CG;
    if (i < CX) {
        int n = i / K1P, k = i - n * K1P;
        x0[i] = (k < 92) ? f2bf(nf[(size_t)n * 92 + k]) : (ushort)0;
        return;
    }
    i -= CX;
    if (i < NNODES) { gate[i] = 0.f; return; }
    i -= NNODES;
    if (i < NNODES) { deg[i] = 0; return; }
    i -= NNODES;
    if (i <= NGRAPH) {
        int lo = 0, hi = NNODES;
        while (lo < hi) {
            int mid = (lo + hi) >> 1;
            if (gid[mid] < i) lo = mid + 1; else hi = mid;
        }
        gstart[i] = lo;
    }
}

// ======================== MFMA bf16 GEMM (templated BK, async global_load_lds staging) =====
// grid = (colBlocks, rowBlocks). MODE 0: direct bf16 C store. MODE 1: fused gate epilogue.
// BK=32 (R10-verified): 64B LDS rows, 2-bit XOR swizzle, 1 MFMA sub-step/barrier.
//   stored piece = (l&3)^((srow>>1)&3);  read piece = quad^((l16>>1)&3)
// BK=64 (R11-verified): 128B LDS rows, 3-bit XOR swizzle, 2 MFMA sub-steps/barrier
//   (halves barrier/vmcnt-drain count; used where K % 64 == 0).
//   stored piece = (l&7)^(l>>3);  read piece = (ks*4+quad)^(l16&7)
// OOB A rows (row >= M) read garbage from adjacent ws buffers; outputs masked.
template <int BN, int MODE, int BK>
__global__ __launch_bounds__(256) void mfma_gemm(const ushort* __restrict__ A,
                                                 const ushort* __restrict__ Bt,
                                                 const float* __restrict__ bias,
                                                 ushort* __restrict__ C,
                                                 const float* __restrict__ Wg2,
                                                 float* __restrict__ gate,
                                                 int M, int K, int N) {
    constexpr int WNS = BN / 2;
    constexpr int NT = WNS / 16;
    __shared__ ushort Alds[128][BK];
    __shared__ ushort Blds[BN][BK];
    int tid = threadIdx.x;
    int wave = tid >> 6, lane = tid & 63;
    int wm = wave & 1, wn = wave >> 1;
    int quad = lane >> 4, l16 = lane & 15;
    int rowBase = blockIdx.y * 128;
    int colBase = blockIdx.x * BN;

    f32x4 acc[4][NT];
#pragma unroll
    for (int i = 0; i < 4; i++)
#pragma unroll
        for (int j = 0; j < NT; j++) acc[i][j] = (f32x4){0.f, 0.f, 0.f, 0.f};

    if constexpr (BK == 32) {
        // staging: chunk = 16 rows x 64B; lane -> (row l>>2, swizzled 16B piece)
        int srow = lane >> 2;
        int scol = ((lane & 3) ^ ((srow >> 1) & 3)) * 8;
        int rp = (quad ^ ((l16 >> 1) & 3)) * 8;
        for (int k0 = 0; k0 < K; k0 += 32) {
#pragma unroll
            for (int c = 0; c < 2; c++) {
                int chunk = wave * 2 + c;
                int row = rowBase + chunk * 16 + srow;
                async_copy16(&A[(size_t)row * K + k0 + scol], &Alds[chunk * 16][0]);
            }
            if constexpr (BN == 128) {
#pragma unroll
                for (int c = 0; c < 2; c++) {
                    int chunk = wave * 2 + c;
                    int row = colBase + chunk * 16 + srow;
                    async_copy16(&Bt[(size_t)row * K + k0 + scol], &Blds[chunk * 16][0]);
                }
            } else {
                int row = colBase + wave * 16 + srow;
                async_copy16(&Bt[(size_t)row * K + k0 + scol], &Blds[wave * 16][0]);
            }
            __syncthreads();
            bf16x8 af[4], bf[NT];
#pragma unroll
            for (int i = 0; i < 4; i++)
                af[i] = *(const bf16x8*)&Alds[wm * 64 + i * 16 + l16][rp];
#pragma unroll
            for (int j = 0; j < NT; j++)
                bf[j] = *(const bf16x8*)&Blds[wn * WNS + j * 16 + l16][rp];
#pragma unroll
            for (int i = 0; i < 4; i++)
#pragma unroll
                for (int j = 0; j < NT; j++)
                    acc[i][j] = __builtin_amdgcn_mfma_f32_16x16x32_bf16(af[i], bf[j], acc[i][j], 0, 0, 0);
            __syncthreads();
        }
    } else {
        // staging: chunk = 8 rows x 128B; lane -> (row l>>3, swizzled 16B piece)
        int srow8 = lane >> 3;
        int scol = ((lane & 7) ^ srow8) * 8;
        int rp0 = ((quad) ^ (l16 & 7)) * 8;
        int rp1 = ((4 + quad) ^ (l16 & 7)) * 8;
        for (int k0 = 0; k0 < K; k0 += 64) {
#pragma unroll
            for (int c = 0; c < 4; c++) {
                int chunk = wave * 4 + c;
                int row = rowBase + chunk * 8 + srow8;
                async_copy16(&A[(size_t)row * K + k0 + scol], &Alds[chunk * 8][0]);
            }
            if constexpr (BN == 128) {
#pragma unroll
                for (int c = 0; c < 4; c++) {
                    int chunk = wave * 4 + c;
                    int row = colBase + chunk * 8 + srow8;
                    async_copy16(&Bt[(size_t)row * K + k0 + scol], &Blds[chunk * 8][0]);
                }
            } else {
#pragma unroll
                for (int c = 0; c < 2; c++) {
                    int chunk = wave * 2 + c;
                    int row = colBase + chunk * 8 + srow8;
                    async_copy16(&Bt[(size_t)row * K + k0 + scol], &Blds[chunk * 8][0]);
                }
            }
            __syncthreads();
            {
                bf16x8 af[4], bf[NT];
#pragma unroll
                for (int i = 0; i < 4; i++)
                    af[i] = *(const bf16x8*)&Alds[wm * 64 + i * 16 + l16][rp0];
#pragma unroll
                for (int j = 0; j < NT; j++)
                    bf[j] = *(const bf16x8*)&Blds[wn * WNS + j * 16 + l16][rp0];
#pragma unroll
                for (int i = 0; i < 4; i++)
#pragma unroll
                    for (int j = 0; j < NT; j++)
                        acc[i][j] = __builtin_amdgcn_mfma_f32_16x16x32_bf16(af[i], bf[j], acc[i][j], 0, 0, 0);
            }
            {
                bf16x8 af[4], bf[NT];
#pragma unroll
                for (int i = 0; i < 4; i++)
                    af[i] = *(const bf16x8*)&Alds[wm * 64 + i * 16 + l16][rp1];
#pragma unroll
                for (int j = 0; j < NT; j++)
                    bf[j] = *(const bf16x8*)&Blds[wn * WNS + j * 16 + l16][rp1];
#pragma unroll
                for (int i = 0; i < 4; i++)
#pragma unroll
                    for (int j = 0; j < NT; j++)
                        acc[i][j] = __builtin_amdgcn_mfma_f32_16x16x32_bf16(af[i], bf[j], acc[i][j], 0, 0, 0);
            }
            __syncthreads();
        }
    }

    if constexpr (MODE == 0) {
#pragma unroll
        for (int i = 0; i < 4; i++) {
#pragma unroll
            for (int j = 0; j < NT; j++) {
                int col = colBase + wn * WNS + j * 16 + l16;
#pragma unroll
                for (int r = 0; r < 4; r++) {
                    int row = rowBase + wm * 64 + i * 16 + quad * 4 + r;
                    if (row < M) C[(size_t)row * N + col] = f2bf(acc[i][j][r]);
                }
            }
        }
    } else {
        float bb[NT], wg[NT];
#pragma unroll
        for (int j = 0; j < NT; j++) {
            int col = colBase + wn * WNS + j * 16 + l16;
            bb[j] = bias[col];
            wg[j] = Wg2[col];
        }
#pragma unroll
        for (int i = 0; i < 4; i++) {
            float pd[4] = {0.f, 0.f, 0.f, 0.f};
#pragma unroll
            for (int j = 0; j < NT; j++) {
#pragma unroll
                for (int r = 0; r < 4; r++) {
                    float x = fmaxf(acc[i][j][r] + bb[j], 0.f);
                    pd[r] = fmaf(x, wg[j], pd[r]);
                }
            }
#pragma unroll
            for (int m = 1; m < 16; m <<= 1)
#pragma unroll
                for (int r = 0; r < 4; r++)
                    pd[r] += __shfl_xor(pd[r], m, 64);
            if (l16 == 0) {
#pragma unroll
                for (int r = 0; r < 4; r++) {
                    int row = rowBase + wm * 64 + i * 16 + quad * 4 + r;
                    if (row < M) atomicAdd(&gate[row], pd[r]);
                }
            }
        }
    }
}

// ======================== el/er: multi-node-per-wave, vectorized ========================
template <int HD>
__global__ __launch_bounds__(256) void eler_node(const ushort* __restrict__ Wh,
                                                 const float* __restrict__ al,
                                                 const float* __restrict__ ar,
                                                 float* __restrict__ el,
                                                 float* __restrict__ er) {
    constexpr int LPN = HD / 8;
    constexpr int NPW = 64 / LPN;
    constexpr int S = (HD / NHEAD) / 8;
    int wave = threadIdx.x >> 6;
    int lane = threadIdx.x & 63;
    int sub = lane & (LPN - 1);
    int n = blockIdx.x * (4 * NPW) + wave * NPW + lane / LPN;
    int d0 = sub * 8;
    uint4 v = *(const uint4*)&Wh[(size_t)n * HD + d0];
    float w0 = bflo(v.x), w1 = bfhi(v.x), w2 = bflo(v.y), w3 = bfhi(v.y);
    float w4 = bflo(v.z), w5 = bfhi(v.z), w6 = bflo(v.w), w7 = bfhi(v.w);
    float4 a0 = *(const float4*)&al[d0];
    float4 a1 = *(const float4*)&al[d0 + 4];
    float4 b0 = *(const float4*)&ar[d0];
    float4 b1 = *(const float4*)&ar[d0 + 4];
    float sl, sr;
    sl = w0 * a0.x; sl = fmaf(w1, a0.y, sl); sl = fmaf(w2, a0.z, sl); sl = fmaf(w3, a0.w, sl);
    sl = fmaf(w4, a1.x, sl); sl = fmaf(w5, a1.y, sl); sl = fmaf(w6, a1.z, sl); sl = fmaf(w7, a1.w, sl);
    sr = w0 * b0.x; sr = fmaf(w1, b0.y, sr); sr = fmaf(w2, b0.z, sr); sr = fmaf(w3, b0.w, sr);
    sr = fmaf(w4, b1.x, sr); sr = fmaf(w5, b1.y, sr); sr = fmaf(w6, b1.z, sr); sr = fmaf(w7, b1.w, sr);
#pragma unroll
    for (int o = S / 2; o > 0; o >>= 1) {
        sl += __shfl_down(sl, o, 64);
        sr += __shfl_down(sr, o, 64);
    }
    if ((sub & (S - 1)) == 0) {
        int h = sub / S;
        el[n * 4 + h] = sl;
        er[n * 4 + h] = sr;
    }
}

// ======================== edge-parallel attn: one thread per CSR slot ========================
// w = exp(leaky(el[src]+er[dst]) - 8): fixed shift replaces per-node max (softmax
// shift-invariance; scores O(1), overflow needs >96, denominator underflow needs all
// < -12 — impossible here). Fully parallel: 800k threads, no per-node serial loop.
// Denominator is accumulated inside the aggregate (1 VALU add per edge per lane).
__global__ void attn_edge(const int* __restrict__ src_csr, const int* __restrict__ dst_csr,
                          const float4* __restrict__ el4, const float4* __restrict__ er4,
                          float4* __restrict__ aw4) {
    int i = blockIdx.x * blockDim.x + threadIdx.x;
    if (i >= NEDGES) return;
    int s = src_csr[i];
    int d = dst_csr[i];
    float4 a = el4[s];
    float4 b = er4[d];
    float x0 = a.x + b.x, x1 = a.y + b.y, x2 = a.z + b.z, x3 = a.w + b.w;
    x0 = (x0 >= 0.f) ? x0 : 0.2f * x0;
    x1 = (x1 >= 0.f) ? x1 : 0.2f * x1;
    x2 = (x2 >= 0.f) ? x2 : 0.2f * x2;
    x3 = (x3 >= 0.f) ? x3 : 0.2f * x3;
    float4 w;
    w.x = expf(x0 - 8.f); w.y = expf(x1 - 8.f);
    w.z = expf(x2 - 8.f); w.w = expf(x3 - 8.f);
    aw4[i] = w;
}

// ======================== aggregate v2b: wave/node, SGPR gather, local denominator ========
// Wave w of block b owns node n = b*4 + w. Lane covers DPL dims starting at
// pass*64*DPL + lane*DPL. Src indices / offsets forced to SGPRs via readfirstlane ->
// SALU addressing, saddr-form gathers. Softmax denominator accumulated from the
// weights each lane loads anyway (1 add/edge; lanes sharing a head duplicate it).
template <int HD, int DPL>
__global__ __launch_bounds__(256) void gat_aggregate2(const int* __restrict__ src_csr,
                                                      const int* __restrict__ off,
                                                      const ushort* __restrict__ Wh,
                                                      const float* __restrict__ aw,
                                                      const float* __restrict__ bias,
                                                      ushort* __restrict__ out,
                                                      int pass) {
    constexpr int LOGD = (HD == 128) ? 5 : (HD == 256) ? 6 : 7;
    const int lane = threadIdx.x & 63;
    const int wv = __builtin_amdgcn_readfirstlane((int)(threadIdx.x >> 6));
    const int n = blockIdx.x * 4 + wv;
    const int d = pass * (64 * DPL) + lane * DPL;
    const int h = d >> LOGD;
    const int i0 = __builtin_amdgcn_readfirstlane(off[n]);
    const int i1 = __builtin_amdgcn_readfirstlane(off[n + 1]);

    float a0 = 0.f, a1 = 0.f, a2 = 0.f, a3 = 0.f;
    float ssum = 0.f;
    const ushort* __restrict__ col = Wh + d;  // per-lane column base; row offset is SGPR

    int i = i0;
    for (; i + 4 <= i1; i += 4) {
        const int s0 = __builtin_amdgcn_readfirstlane(src_csr[i + 0]);
        const int s1 = __builtin_amdgcn_readfirstlane(src_csr[i + 1]);
        const int s2 = __builtin_amdgcn_readfirstlane(src_csr[i + 2]);
        const int s3 = __builtin_amdgcn_readfirstlane(src_csr[i + 3]);
        const float w0 = aw[(i + 0) * 4 + h];
        const float w1 = aw[(i + 1) * 4 + h];
        const float w2 = aw[(i + 2) * 4 + h];
        const float w3 = aw[(i + 3) * 4 + h];
        ssum += w0; ssum += w1; ssum += w2; ssum += w3;
        if constexpr (DPL == 4) {
            uint2 v0 = *(const uint2*)&col[(size_t)s0 * HD];
            uint2 v1 = *(const uint2*)&col[(size_t)s1 * HD];
            uint2 v2 = *(const uint2*)&col[(size_t)s2 * HD];
            uint2 v3 = *(const uint2*)&col[(size_t)s3 * HD];
            fmabf2(w0, v0.x, a0, a1); fmabf2(w0, v0.y, a2, a3);
            fmabf2(w1, v1.x, a0, a1); fmabf2(w1, v1.y, a2, a3);
            fmabf2(w2, v2.x, a0, a1); fmabf2(w2, v2.y, a2, a3);
            fmabf2(w3, v3.x, a0, a1); fmabf2(w3, v3.y, a2, a3);
        } else {
            uint v0 = *(const uint*)&col[(size_t)s0 * HD];
            uint v1 = *(const uint*)&col[(size_t)s1 * HD];
            uint v2 = *(const uint*)&col[(size_t)s2 * HD];
            uint v3 = *(const uint*)&col[(size_t)s3 * HD];
            fmabf2(w0, v0, a0, a1);
            fmabf2(w1, v1, a0, a1);
            fmabf2(w2, v2, a0, a1);
            fmabf2(w3, v3, a0, a1);
        }
    }
    for (; i < i1; ++i) {
        const int s0 = __builtin_amdgcn_readfirstlane(src_csr[i]);
        const float w0 = aw[i * 4 + h];
        ssum += w0;
        if constexpr (DPL == 4) {
            uint2 v0 = *(const uint2*)&col[(size_t)s0 * HD];
            fmabf2(w0, v0.x, a0, a1); fmabf2(w0, v0.y, a2, a3);
        } else {
            uint v0 = *(const uint*)&col[(size_t)s0 * HD];
            fmabf2(w0, v0, a0, a1);
        }
    }

    const float inv = 1.f / fmaxf(ssum, 1e-9f);
    float x0 = a0 * inv + bias[d + 0];
    float x1 = a1 * inv + bias[d + 1];
    x0 = (x0 > 0.f) ? x0 : (expf(x0) - 1.f);
    x1 = (x1 > 0.f) ? x1 : (expf(x1) - 1.f);
    if constexpr (DPL == 4) {
        float x2 = a2 * inv + bias[d + 2];
        float x3 = a3 * inv + bias[d + 3];
        x2 = (x2 > 0.f) ? x2 : (expf(x2) - 1.f);
        x3 = (x3 > 0.f) ? x3 : (expf(x3) - 1.f);
        uint2 o;
        o.x = pack2(x0, x1);
        o.y = pack2(x2, x3);
        *(uint2*)&out[(size_t)n * HD + d] = o;
    } else {
        *(uint*)&out[(size_t)n * HD + d] = pack2(x0, x1);
    }
}

// ======================== pooled partial sums + fused per-graph softmax ========================
// Each block (g,q) recomputes its graph's gate max m (deterministic: identical
// strided partition + LDS tree in every block of graph g), then pools its node
// chunk with w = exp(gate-m). Denominator is applied in final_kernel.
__global__ __launch_bounds__(128) void pool_partial(const ushort* __restrict__ h,
                                                    const float* __restrict__ gate,
                                                    const int* __restrict__ gstart,
                                                    float* __restrict__ partial) {
    int g = blockIdx.x, q = blockIdx.y;
    int n0 = gstart[g], n1 = gstart[g + 1];
    __shared__ float red[128];
    int t = threadIdx.x;
    float m = -1e30f;
    for (int n = n0 + t; n < n1; n += 128) m = fmaxf(m, gate[n]);
    red[t] = m; __syncthreads();
    for (int s = 64; s > 0; s >>= 1) {
        if (t < s) red[t] = fmaxf(red[t], red[t + s]);
        __syncthreads();
    }
    m = red[0];

    int len = n1 - n0;
    int chunk = (len + PQ - 1) / PQ;
    int s = n0 + q * chunk;
    int e = s + chunk; if (e > n1) e = n1;
    int d4 = t;
    const uint2* h2 = (const uint2*)h;
    float a0 = 0.f, a1 = 0.f, a2 = 0.f, a3 = 0.f;
    for (int n = s; n < e; n++) {
        float w = expf(gate[n] - m);
        uint2 v = h2[(size_t)n * 128 + d4];
        a0 = fmaf(w, bflo(v.x), a0);
        a1 = fmaf(w, bfhi(v.x), a1);
        a2 = fmaf(w, bflo(v.y), a2);
        a3 = fmaf(w, bfhi(v.y), a3);
    }
    *(float4*)&partial[((size_t)(g * PQ + q)) * FINALD + d4 * 4] = make_float4(a0, a1, a2, a3);
}

// ======================== final heads (computes graph softmax denominator) ========================
__global__ __launch_bounds__(128) void final_kernel(const float* __restrict__ partial,
                                                    const float* __restrict__ gate,
                                                    const int* __restrict__ gstart,
                                                    const float* __restrict__ Wmu,
                                                    const float* __restrict__ bmu,
                                                    const float* __restrict__ Wlv,
                                                    const float* __restrict__ blv,
                                                    float* __restrict__ out) {
    int g = blockIdx.x, j = threadIdx.x;
    int n0 = gstart[g], n1 = gstart[g + 1];
    __shared__ float red[128];
    __shared__ float pooled[FINALD];
    // gsum = sum exp(gate - m), same deterministic m as pool_partial
    float m = -1e30f;
    for (int n = n0 + j; n < n1; n += 128) m = fmaxf(m, gate[n]);
    red[j] = m; __syncthreads();
    for (int s = 64; s > 0; s >>= 1) {
        if (j < s) red[j] = fmaxf(red[j], red[j + s]);
        __syncthreads();
    }
    m = red[0]; __syncthreads();
    float sum = 0.f;
    for (int n = n0 + j; n < n1; n += 128) sum += expf(gate[n] - m);
    red[j] = sum; __syncthreads();
    for (int s = 64; s > 0; s >>= 1) {
        if (j < s) red[j] += red[j + s];
        __syncthreads();
    }
    float gsum = red[0];

    const float* p = partial + (size_t)g * PQ * FINALD;
    for (int k = j; k < FINALD; k += 128) {
        float v = 0.f;
#pragma unroll
        for (int q = 0; q < PQ; q++) v += p[q * FINALD + k];
        pooled[k] = v;
    }
    __syncthreads();
    float am = 0.f, av = 0.f;
    for (int k = 0; k < FINALD; k++) {
        float pv = pooled[k];
        am = fmaf(pv, Wmu[k * LATD + j], am);
        av = fmaf(pv, Wlv[k * LATD + j], av);
    }
    float inv = 1.f / fmaxf(gsum, 1e-9f);
    out[g * LATD + j] = am * inv + bmu[j];
    out[NGRAPH * LATD + g * LATD + j] = av * inv + blv[j];
}

// ======================== driver ========================
extern "C" void kernel_launch(void* const* d_in, const int* in_sizes, int n_in,
                              void* d_out, int out_size, void* d_ws, size_t ws_size,
                              hipStream_t stream) {
    (void)in_sizes; (void)n_in; (void)out_size; (void)ws_size;
    const float* node_feat = (const float*)d_in[0];
    const int* src = (const int*)d_in[1];
    const int* dst = (const int*)d_in[2];
    const int* gid = (const int*)d_in[3];
    const float* W[3]    = {(const float*)d_in[4],  (const float*)d_in[8],  (const float*)d_in[12]};
    const float* al[3]   = {(const float*)d_in[5],  (const float*)d_in[9],  (const float*)d_in[13]};
    const float* ar[3]   = {(const float*)d_in[6],  (const float*)d_in[10], (const float*)d_in[14]};
    const float* bias[3] = {(const float*)d_in[7],  (const float*)d_in[11], (const float*)d_in[15]};
    const float* Wg1 = (const float*)d_in[16];
    const float* bg1 = (const float*)d_in[17];
    const float* Wg2 = (const float*)d_in[18];
    // bg2 cancels in the node softmax — unused.
    const float* Wmu = (const float*)d_in[20];
    const float* bmu = (const float*)d_in[21];
    const float* Wlv = (const float*)d_in[22];
    const float* blv = (const float*)d_in[23];

    char* ws = (char*)d_ws;
    size_t woff = 0;
    auto carve = [&](size_t bytes) {
        void* p = ws + woff;
        woff = (woff + bytes + 255) & ~(size_t)255;
        return p;
    };
    ushort* hA      = (ushort*)carve((size_t)NNODES * 512 * 2);
    ushort* hB      = (ushort*)carve((size_t)NNODES * 512 * 2);
    float*  el      = (float*) carve((size_t)NNODES * 4 * 4);
    float*  er      = (float*) carve((size_t)NNODES * 4 * 4);
    float*  aw      = (float*) carve((size_t)NEDGES * 4 * 4);
    int*    deg     = (int*)   carve((size_t)NNODES * 4);
    int*    off     = (int*)   carve((size_t)(NNODES + 1) * 4);
    int*    cursor  = (int*)   carve((size_t)NNODES * 4);
    int*    src_csr = (int*)   carve((size_t)NEDGES * 4);
    int*    dst_csr = (int*)   carve((size_t)NEDGES * 4);
    int*    bsum    = (int*)   carve((size_t)(NB_SCAN + 1) * 4);
    float*  gate    = (float*) carve((size_t)NNODES * 4);
    int*    gstart  = (int*)   carve((size_t)(NGRAPH + 1) * 4);
    float*  partial = (float*) carve((size_t)NGRAPH * PQ * FINALD * 4);
    ushort* Bt1     = (ushort*)carve((size_t)128 * K1P * 2);
    ushort* Bt2     = (ushort*)carve((size_t)256 * 128 * 2);
    ushort* Bt3     = (ushort*)carve((size_t)512 * 256 * 2);
    ushort* Btg     = (ushort*)carve((size_t)64 * 512 * 2 + 4096);  // +4KB guard for async OOB reads
    ushort* x0      = hA;  // alias: x0 dead before hA first written (L1 aggregate)

    // ---- setup (6 launches; conv_all also zeros deg/gate + computes gstart) ----
    conv_all_kernel<<<(CTOT + 255) / 256, 256, 0, stream>>>(
        W[0], W[1], W[2], Wg1, node_feat, Bt1, Bt2, Bt3, Btg, x0, gate, deg, gid, gstart);
    count_kernel<<<(NEDGES + 255) / 256, 256, 0, stream>>>(dst, deg);
    scan_block_kernel<<<NB_SCAN, 1024, 0, stream>>>(deg, off, bsum);
    scan_bsum_kernel<<<1, 128, 0, stream>>>(bsum);
    scan_add_kernel<<<NB_SCAN, 1024, 0, stream>>>(off, bsum, cursor);
    scatter_kernel<<<(NEDGES + 255) / 256, 256, 0, stream>>>(src, dst, cursor, src_csr, dst_csr);

    const int MB = (NNODES + 127) / 128;  // 782
    const int AGB = NNODES / 4;           // 25000 blocks, 4 waves (nodes) each
    const int EB = (NEDGES + 255) / 256;  // 3125 edge blocks

    // ---- layer 1 (K=96, BK=32 path — no padding tax) ----
    mfma_gemm<128, 0, 32><<<dim3(1, MB), 256, 0, stream>>>(
        x0, Bt1, nullptr, hB, nullptr, nullptr, NNODES, K1P, 128);
    eler_node<128><<<NNODES / 16, 256, 0, stream>>>(hB, al[0], ar[0], el, er);
    attn_edge<<<EB, 256, 0, stream>>>(
        src_csr, dst_csr, (const float4*)el, (const float4*)er, (float4*)aw);
    gat_aggregate2<128, 2><<<AGB, 256, 0, stream>>>(
        src_csr, off, hB, aw, bias[0], hA, 0);

    // ---- layer 2 (K=128, BK=64) ----
    mfma_gemm<128, 0, 64><<<dim3(2, MB), 256, 0, stream>>>(
        hA, Bt2, nullptr, hB, nullptr, nullptr, NNODES, 128, 256);
    eler_node<256><<<NNODES / 8, 256, 0, stream>>>(hB, al[1], ar[1], el, er);
    attn_edge<<<EB, 256, 0, stream>>>(
        src_csr, dst_csr, (const float4*)el, (const float4*)er, (float4*)aw);
    gat_aggregate2<256, 4><<<AGB, 256, 0, stream>>>(
        src_csr, off, hB, aw, bias[1], hA, 0);

    // ---- layer 3 (K=256, BK=64; two dim-pass aggregates: measured champion config) ----
    mfma_gemm<128, 0, 64><<<dim3(4, MB), 256, 0, stream>>>(
        hA, Bt3, nullptr, hB, nullptr, nullptr, NNODES, 256, 512);
    eler_node<512><<<NNODES / 4, 256, 0, stream>>>(hB, al[2], ar[2], el, er);
    attn_edge<<<EB, 256, 0, stream>>>(
        src_csr, dst_csr, (const float4*)el, (const float4*)er, (float4*)aw);
    gat_aggregate2<512, 4><<<AGB, 256, 0, stream>>>(
        src_csr, off, hB, aw, bias[2], hA, 0);
    gat_aggregate2<512, 4><<<AGB, 256, 0, stream>>>(
        src_csr, off, hB, aw, bias[2], hA, 1);

    // ---- attention pooling + heads (K=512, BK=64 gate GEMM) ----
    mfma_gemm<64, 1, 64><<<dim3(1, MB), 256, 0, stream>>>(
        hA, Btg, bg1, nullptr, Wg2, gate, NNODES, FINALD, HIDG);
    pool_partial<<<dim3(NGRAPH, PQ), 128, 0, stream>>>(hA, gate, gstart, partial);
    final_kernel<<<NGRAPH, 128, 0, stream>>>(partial, gate, gstart, Wmu, bmu, Wlv, blv, (float*)d_out);
}